// Round 10
// baseline (208.987 us; speedup 1.0000x reference)
//
#include <hip/hip_runtime.h>
#include <hip/hip_fp16.h>

// GAE reverse affine scan + standardize — fat-stream k_desc + proven k_scan/k_apply.
// adv_k = delta_k + c_k*adv_{k+1}; delta_k = r_k + g*V_{k+1}*nd_k - V_k; c_k = g*l*nd_k.
// k_desc: thread owns 64 CONTIGUOUS elems (16 float4 rounds, 2-deep rotation);
//   lane-local 7-tuple monoid fold {D,C,A,P,L2,LP,P2} (zero shuffles in hot loop);
//   4-step 16-lane-group suffix scan emits per-1024-chunk desc+moments (same layout as R9);
//   persists fp16 delta (linear, 32 MB) + thread-major done-bits u64 (2 MB).
// k_scan: R9-proven (16384 descs -> carries + mean/std).
// k_apply: R9-proven geometry; only mask decode changed to thread-major layout.

#define GAMMA_F 0.99f
#define GL_F 0.9405f            // 0.99*0.95
#define EPS_F 1e-8f

constexpr int NT = 256;
constexpr int SEG = 64;          // contiguous elems per thread
constexpr int NRND = SEG / 4;    // 16 rounds
constexpr int NBLK = 1024;       // 262144 threads * 64 = 16777216
constexpr int PL = 8;            // k_apply: elems per lane
constexpr int TILE = 512;        // k_apply tile
constexpr int CHUNK = 1024;      // carry granularity
constexpr int K2T = 1024;

union H8 { __half h[8]; float4 f4; };

// ---------------- Pass 1: fat-stream desc ----------------
__global__ __launch_bounds__(NT) void k_desc(const float* __restrict__ r,
                                             const float* __restrict__ v,
                                             const int* __restrict__ dn,
                                             float2* __restrict__ desc,
                                             float4* __restrict__ mom4,
                                             float* __restrict__ mom1,
                                             unsigned long long* __restrict__ dmask2,
                                             __half* __restrict__ dh) {
    const int tid = threadIdx.x, lane = tid & 63;
    const int gtid = blockIdx.x * NT + tid;
    const int wid = gtid >> 6;                 // global wave id (4096)
    const size_t e0 = (size_t)gtid * SEG;
    const float4* rp = (const float4*)(r + e0);
    const float4* vp = (const float4*)(v + e0);
    const int4*   dp = (const int4*)(dn + e0);

    // running 7-tuple (identity) over rounds processed so far (left of current)
    float aD = 0.f, aC = 1.f, aA = 0.f, aP = 0.f, aL2 = 0.f, aLP = 0.f, aP2 = 0.f;
    unsigned long long mbits = 0ull;
    unsigned p01 = 0u, p23 = 0u;               // fp16 staging (even round)

    float4 Rr[2], Vv[2]; int4 Dd[2]; float V4[2];
    Rr[0] = rp[0]; Vv[0] = vp[0]; Dd[0] = dp[0]; V4[0] = v[e0 + 4];
#pragma unroll
    for (int t = 0; t < NRND; ++t) {
        const int cur = t & 1, nxt = cur ^ 1;
        if (t + 1 < NRND) {
            Rr[nxt] = rp[t + 1]; Vv[nxt] = vp[t + 1]; Dd[nxt] = dp[t + 1];
            V4[nxt] = v[e0 + 4 * (t + 1) + 4];      // v has T+1 elems; max = e0+64 OK
        }
        const float4 rr = Rr[cur], vv = Vv[cur];
        const int4 dd = Dd[cur];
        const float v4 = V4[cur];

        const float nd0 = 1.f - (float)dd.x, nd1 = 1.f - (float)dd.y;
        const float nd2 = 1.f - (float)dd.z, nd3 = 1.f - (float)dd.w;
        const float d0 = rr.x + GAMMA_F * vv.y * nd0 - vv.x;
        const float d1 = rr.y + GAMMA_F * vv.z * nd1 - vv.y;
        const float d2 = rr.z + GAMMA_F * vv.w * nd2 - vv.z;
        const float d3 = rr.w + GAMMA_F * v4   * nd3 - vv.w;
        const float c0 = GL_F * nd0, c1 = GL_F * nd1, c2 = GL_F * nd2, c3 = GL_F * nd3;

        const unsigned long long nib = (unsigned long long)((dd.x & 1) | ((dd.y & 1) << 1) |
                                                            ((dd.z & 1) << 2) | ((dd.w & 1) << 3));
        mbits |= nib << (4 * t);

        __half2 h01 = __floats2half2_rn(d0, d1);
        __half2 h23 = __floats2half2_rn(d2, d3);
        const unsigned q01 = __builtin_bit_cast(unsigned, h01);
        const unsigned q23 = __builtin_bit_cast(unsigned, h23);
        if ((t & 1) == 0) { p01 = q01; p23 = q23; }
        else {
            *(uint4*)(dh + e0 + 4 * (t - 1)) = make_uint4(p01, p23, q01, q23);
        }

        // round tuple via right-to-left local fold (entry 0 at round's right edge)
        float x = d3, P = c3;
        float A = x, Pp = P, L2 = x * x, LP = x * P, P2 = P * P;
        x = d2 + c2 * x; P *= c2; A += x; Pp += P; L2 += x * x; LP += x * P; P2 += P * P;
        x = d1 + c1 * x; P *= c1; A += x; Pp += P; L2 += x * x; LP += x * P; P2 += P * P;
        x = d0 + c0 * x; P *= c0; A += x; Pp += P; L2 += x * x; LP += x * P; P2 += P * P;
        // acc = acc(left) ∘ round(right):  Drnd=x, Crnd=P
        const float nA  = aA + x * aP + A;
        const float nL2 = aL2 + 2.f * x * aLP + x * x * aP2 + L2;
        const float nLP = P * (aLP + x * aP2) + LP;
        const float nP2 = P * P * aP2 + P2;
        const float nP  = P * aP + Pp;
        const float nD  = aD + aC * x;
        aC = aC * P; aD = nD;
        aA = nA; aP = nP; aL2 = nL2; aLP = nLP; aP2 = nP2;
    }
    dmask2[gtid] = mbits;

    // 16-lane-group suffix scan of thread tuples (4 steps): at lane 16q,
    // tuple = compose of lanes [16q..16q+15] = the 1024-elem sub-chunk.
#pragma unroll
    for (int off = 1; off < 16; off <<= 1) {
        const float tD  = __shfl_down(aD,  off);
        const float tC  = __shfl_down(aC,  off);
        const float tA  = __shfl_down(aA,  off);
        const float tP  = __shfl_down(aP,  off);
        const float tL2 = __shfl_down(aL2, off);
        const float tLP = __shfl_down(aLP, off);
        const float tP2 = __shfl_down(aP2, off);
        if ((lane & 15) + off < 16) {
            const float nA  = aA + tD * aP + tA;
            const float nL2 = aL2 + 2.f * tD * aLP + tD * tD * aP2 + tL2;
            const float nLP = tC * (aLP + tD * aP2) + tLP;
            const float nP2 = tC * tC * aP2 + tP2;
            const float nP  = tC * aP + tP;
            const float nD  = aD + aC * tD;
            aC = aC * tC; aD = nD;
            aA = nA; aP = nP; aL2 = nL2; aLP = nLP; aP2 = nP2;
        }
    }
    if ((lane & 15) == 0) {
        const int ch = wid * 4 + (lane >> 4);   // matches k_apply's chunk numbering
        desc[ch] = make_float2(aD, aC);
        mom4[ch] = make_float4(aA, aP, aL2, aLP);
        mom1[ch] = aP2;
    }
}

// ---------------- Pass 2: scan 16384 descs -> carries + mean/std (R9-proven) ----------------
__global__ __launch_bounds__(K2T) void k_scan(const float2* __restrict__ desc,
                                              const float4* __restrict__ mom4,
                                              const float* __restrict__ mom1,
                                              float* __restrict__ carry,
                                              float2* __restrict__ meanstd,
                                              int nchunk, long long T) {
    const int t = threadIdx.x, lane = t & 63, wv = t >> 6;   // 16 waves
    const int per = nchunk / K2T;   // 16
    const int s = t * per;
    float D = 0.f, C = 1.f;
    for (int i = per - 1; i >= 0; --i) { float2 a = desc[s + i]; D = a.x + a.y * D; C *= a.y; }
    float sD = D, sC = C;
#pragma unroll
    for (int off = 1; off < 64; off <<= 1) {
        float tD = __shfl_down(sD, off), tC = __shfl_down(sC, off);
        if (lane + off < 64) { sD = sD + sC * tD; sC = sC * tC; }
    }
    __shared__ float2 waff[16];
    if (lane == 0) waff[wv] = make_float2(sD, sC);
    __syncthreads();
    float xw = 0.f;
    for (int w = 15; w > wv; --w) xw = waff[w].x + waff[w].y * xw;
    float S1D = __shfl_down(sD, 1), S1C = __shfl_down(sC, 1);
    if (lane == 63) { S1D = 0.f; S1C = 1.f; }
    float x = S1D + S1C * xw;
    double gS = 0.0, gQ = 0.0;
    for (int i = per - 1; i >= 0; --i) {
        const int cix = s + i;
        carry[cix] = x;
        float4 m = mom4[cix];
        float p2 = mom1[cix];
        gS += (double)(m.x + x * m.y);
        gQ += (double)(m.z + 2.f * x * m.w + x * x * p2);
        float2 a = desc[cix];
        x = a.x + a.y * x;
    }
#pragma unroll
    for (int off = 32; off > 0; off >>= 1) {
        gS += __shfl_down(gS, off);
        gQ += __shfl_down(gQ, off);
    }
    __shared__ double Sa[16], Sb[16];
    if (lane == 0) { Sa[wv] = gS; Sb[wv] = gQ; }
    __syncthreads();
    if (t == 0) {
        double S = 0.0, Q = 0.0;
        for (int w = 0; w < 16; ++w) { S += Sa[w]; Q += Sb[w]; }
        double mean = S / (double)T;
        double var = Q / (double)T - mean * mean;
        double sd = sqrt(var > 0.0 ? var : 0.0);
        meanstd[0] = make_float2((float)mean, (float)(1.0 / (sd + (double)EPS_F)));
    }
}

// wave suffix scan of 8 per-lane affines (k_apply helper, R9-proven)
__device__ __forceinline__ void scan8(const float* d, const float* c, int lane,
                                      float& sD, float& sC, float& S1D, float& S1C) {
    float D = 0.f, C = 1.f;
#pragma unroll
    for (int i = 7; i >= 0; --i) { D = d[i] + c[i] * D; C *= c[i]; }
#pragma unroll
    for (int off = 1; off < 64; off <<= 1) {
        float tD = __shfl_down(D, off);
        float tC = __shfl_down(C, off);
        if (lane + off < 64) { D = D + C * tD; C = C * tC; }
    }
    sD = D; sC = C;
    S1D = __shfl_down(D, 1); S1C = __shfl_down(C, 1);
    if (lane == 63) { S1D = 0.f; S1C = 1.f; }
}

// ---------------- Pass 3: fp16 delta + thread-major mask -> out (R9 geometry) ----------------
__global__ __launch_bounds__(NT) void k_apply(const __half* __restrict__ dh,
                                              const unsigned long long* __restrict__ dmask2,
                                              const float* __restrict__ carry,
                                              const float2* __restrict__ meanstd,
                                              float* __restrict__ out) {
    const int tid = threadIdx.x, lane = tid & 63, wv = tid >> 6;
    const int ch = blockIdx.x * 4 + wv;
    const int base = ch * CHUNK;
    const int o0 = base + lane * PL, o1 = base + TILE + lane * PL;

    float d0[8], d1[8];
    H8 u0, u1;
    u0.f4 = *(const float4*)(dh + o0);
    u1.f4 = *(const float4*)(dh + o1);
#pragma unroll
    for (int i = 0; i < 8; ++i) { d0[i] = __half2float(u0.h[i]); d1[i] = __half2float(u1.h[i]); }

    // thread-major mask: bit j of dmask2[j>>6] = done[j]
    const unsigned b0 = (unsigned)((dmask2[(size_t)ch * 16 + (lane >> 3)] >> ((lane & 7) * 8)) & 0xFFull);
    const unsigned b1 = (unsigned)((dmask2[(size_t)ch * 16 + 8 + (lane >> 3)] >> ((lane & 7) * 8)) & 0xFFull);
    float c0[8], c1[8];
#pragma unroll
    for (int i = 0; i < 8; ++i) {
        c0[i] = GL_F * (1.f - (float)((b0 >> i) & 1u));
        c1[i] = GL_F * (1.f - (float)((b1 >> i) & 1u));
    }
    const float2 ms = meanstd[0];
    const float cy = carry[ch];

    float sD1, sC1, S1D1, S1C1;
    scan8(d1, c1, lane, sD1, sC1, S1D1, S1C1);
    const float T1D = __shfl(sD1, 0), T1C = __shfl(sC1, 0);
    float sD0, sC0, S1D0, S1C0;
    scan8(d0, c0, lane, sD0, sC0, S1D0, S1C0);

    float o[8];
    float x = S1D1 + S1C1 * cy;                   // tile1: entry = cy at chunk right edge
#pragma unroll
    for (int i = 7; i >= 0; --i) { x = d1[i] + c1[i] * x; o[i] = (x - ms.x) * ms.y; }
    *(float4*)(out + o1)     = make_float4(o[0], o[1], o[2], o[3]);
    *(float4*)(out + o1 + 4) = make_float4(o[4], o[5], o[6], o[7]);
    const float x0e = T1D + T1C * cy;             // tile0: entry = A_tile1(cy)
    x = S1D0 + S1C0 * x0e;
#pragma unroll
    for (int i = 7; i >= 0; --i) { x = d0[i] + c0[i] * x; o[i] = (x - ms.x) * ms.y; }
    *(float4*)(out + o0)     = make_float4(o[0], o[1], o[2], o[3]);
    *(float4*)(out + o0 + 4) = make_float4(o[4], o[5], o[6], o[7]);
}

extern "C" void kernel_launch(void* const* d_in, const int* in_sizes, int n_in,
                              void* d_out, int out_size, void* d_ws, size_t ws_size,
                              hipStream_t stream) {
    const float* rewards = (const float*)d_in[0];
    const float* v_pred  = (const float*)d_in[1];
    const int*   dones   = (const int*)d_in[2];
    float* out = (float*)d_out;
    const long long T = in_sizes[0];          // 16777216
    const int nchunk = (int)(T / CHUNK);      // 16384

    // workspace layout (ws_size >= 36 MB proven in R6)
    char* ws = (char*)d_ws;
    float4* mom4 = (float4*)ws;                                       // 256 KB
    float2* desc = (float2*)(ws + (size_t)nchunk * 16);               // 128 KB
    float*  mom1 = (float*)(ws + (size_t)nchunk * 24);                // 64 KB
    float*  carry = (float*)(ws + (size_t)nchunk * 28);               // 64 KB
    float2* meanstd = (float2*)(ws + (size_t)nchunk * 32);            // 16 B
    unsigned long long* dmask2 =
        (unsigned long long*)(ws + (size_t)nchunk * 32 + 16);         // 2 MB (thread-major)
    __half* dh = (__half*)(ws + 4ull * 1024 * 1024);                  // 32 MB @ 4 MB

    hipLaunchKernelGGL(k_desc, dim3(NBLK), dim3(NT), 0, stream,
                       rewards, v_pred, dones, desc, mom4, mom1, dmask2, dh);
    hipLaunchKernelGGL(k_scan, dim3(1), dim3(K2T), 0, stream,
                       desc, mom4, mom1, carry, meanstd, nchunk, T);
    hipLaunchKernelGGL(k_apply, dim3(nchunk / 4), dim3(NT), 0, stream,
                       dh, dmask2, carry, meanstd, out);
}

// Round 12
// 117.219 us; speedup vs baseline: 1.7829x; 1.7829x over previous
//
#include <hip/hip_runtime.h>

// GAE reverse affine scan + standardize — L3-residency version (compile-fixed).
// adv_k = delta_k + c_k*adv_{k+1}; delta_k = r_k + g*V_{k+1}*nd_k - V_k; c_k = g*l*nd_k.
// Affine f(x)=D+C*x; compose(left,right) = (Dl+Cl*Dr, Cl*Cr).
// Wave owns a 1024-elem chunk (2 tiles of 512; lane owns 8 contiguous elems).
// Strategy: keep cache pollution ~2 MB so inputs (192 MB) stay Infinity-Cache-resident
// across graph replays: no delta persistence; pass 3 recomputes from (L3-hot) r,v;
// `out` written with nontemporal stores (native ext_vector_type for the builtin).

#define GAMMA_F 0.99f
#define GL_F 0.9405f            // 0.99*0.95
#define EPS_F 1e-8f

constexpr int NT = 256;          // 4 waves per block
constexpr int PL = 8;            // elems per lane
constexpr int TILE = 512;        // elems per wave-tile (64*8)
constexpr int CHUNK = 2 * TILE;  // 1024 elems per wave-chunk
constexpr int K2T = 1024;        // k_scan threads

typedef float f4n __attribute__((ext_vector_type(4)));   // native vec for nontemporal builtin

__device__ __forceinline__ void nt_store4(float* p, float a, float b, float c, float d) {
    f4n v; v.x = a; v.y = b; v.z = c; v.w = d;
    __builtin_nontemporal_store(v, (f4n*)p);
}

// Suffix scan of 8 per-lane affines across the wave.
// sD,sC = A_lane∘...∘A_63 ; S1D,S1C = exclusive (identity at lane 63).
__device__ __forceinline__ void scan8(const float* d, const float* c, int lane,
                                      float& sD, float& sC, float& S1D, float& S1C) {
    float D = 0.f, C = 1.f;
#pragma unroll
    for (int i = 7; i >= 0; --i) { D = d[i] + c[i] * D; C *= c[i]; }
#pragma unroll
    for (int off = 1; off < 64; off <<= 1) {
        float tD = __shfl_down(D, off);
        float tC = __shfl_down(C, off);
        if (lane + off < 64) { D = D + C * tD; C = C * tC; }
    }
    sD = D; sC = C;
    S1D = __shfl_down(D, 1); S1C = __shfl_down(C, 1);
    if (lane == 63) { S1D = 0.f; S1C = 1.f; }
}

// delta/cont for one 512-elem tile from raw inputs, then scan.
__device__ __forceinline__ void tile_scan(const float4& r0, const float4& r1,
                                          const float4& v0, const float4& v1,
                                          const float* nd, float vn63, int lane,
                                          float* d, float* c,
                                          float& sD, float& sC, float& S1D, float& S1C) {
    float vnext = __shfl_down(v0.x, 1);
    if (lane == 63) vnext = vn63;
    float va[9] = {v0.x, v0.y, v0.z, v0.w, v1.x, v1.y, v1.z, v1.w, vnext};
    float rf[8] = {r0.x, r0.y, r0.z, r0.w, r1.x, r1.y, r1.z, r1.w};
#pragma unroll
    for (int i = 0; i < 8; ++i) {
        d[i] = rf[i] + GAMMA_F * va[i + 1] * nd[i] - va[i];
        c[i] = GL_F * nd[i];
    }
    scan8(d, c, lane, sD, sC, S1D, S1C);
}

// Per-lane tile-local moments (entry 0 at tile right edge): {Σloc, ΣP, Σloc², Σloc·P, ΣP²}.
__device__ __forceinline__ void lane_moms(const float* d, const float* c,
                                          float S1D, float S1C, float* mm) {
    float x = S1D, P = S1C;
    float A = 0.f, Pp = 0.f, L2 = 0.f, LP = 0.f, P2 = 0.f;
#pragma unroll
    for (int i = 7; i >= 0; --i) {
        x = d[i] + c[i] * x;
        P *= c[i];
        A += x; Pp += P; L2 += x * x; LP += x * P; P2 += P * P;
    }
    mm[0] = A; mm[1] = Pp; mm[2] = L2; mm[3] = LP; mm[4] = P2;
}

// Pass 1: per-chunk desc + moments + done-mask. No barriers, no LDS. (R5-proven.)
__global__ __launch_bounds__(NT) void k_desc(const float* __restrict__ r,
                                             const float* __restrict__ v,
                                             const int* __restrict__ dn,
                                             float2* __restrict__ desc,
                                             float4* __restrict__ mom4,
                                             float* __restrict__ mom1,
                                             unsigned long long* __restrict__ dmask) {
    const int tid = threadIdx.x, lane = tid & 63, wv = tid >> 6;
    const int ch = blockIdx.x * 4 + wv;
    const int base = ch * CHUNK;
    const int o0 = base + lane * PL, o1 = base + TILE + lane * PL;

    float4 r00 = *(const float4*)(r + o0), r01 = *(const float4*)(r + o0 + 4);
    float4 v00 = *(const float4*)(v + o0), v01 = *(const float4*)(v + o0 + 4);
    int4   a00 = *(const int4*)(dn + o0),  a01 = *(const int4*)(dn + o0 + 4);
    float4 r10 = *(const float4*)(r + o1), r11 = *(const float4*)(r + o1 + 4);
    float4 v10 = *(const float4*)(v + o1), v11 = *(const float4*)(v + o1 + 4);
    int4   a10 = *(const int4*)(dn + o1),  a11 = *(const int4*)(dn + o1 + 4);

    float vn63_t1 = (lane == 63) ? v[base + CHUNK] : 0.f;   // v has T+1 elems
    float vn63_t0 = __shfl(v10.x, 0);

    int di0[8] = {a00.x, a00.y, a00.z, a00.w, a01.x, a01.y, a01.z, a01.w};
    int di1[8] = {a10.x, a10.y, a10.z, a10.w, a11.x, a11.y, a11.z, a11.w};
    float nd0[8], nd1[8];
    unsigned long long m0[8], m1[8];
#pragma unroll
    for (int i = 0; i < 8; ++i) {
        nd0[i] = 1.f - (float)di0[i]; m0[i] = __ballot(di0[i] != 0);
        nd1[i] = 1.f - (float)di1[i]; m1[i] = __ballot(di1[i] != 0);
    }

    float d1[8], c1[8], sD1, sC1, S1D1, S1C1;
    tile_scan(r10, r11, v10, v11, nd1, vn63_t1, lane, d1, c1, sD1, sC1, S1D1, S1C1);
    const float T1D = __shfl(sD1, 0), T1C = __shfl(sC1, 0);
    float d0[8], c0[8], sD0, sC0, S1D0, S1C0;
    tile_scan(r00, r01, v00, v01, nd0, vn63_t0, lane, d0, c0, sD0, sC0, S1D0, S1C0);
    const float T0D = __shfl(sD0, 0), T0C = __shfl(sC0, 0);

    float mm1[5], mm0[5];
    lane_moms(d1, c1, S1D1, S1C1, mm1);
    lane_moms(d0, c0, S1D0, S1C0, mm0);
    const float e = T1D, f = T1C;   // lift tile0 moments through tile1's affine
    float gA  = mm1[0] + mm0[0] + e * mm0[1];
    float gP  = mm1[1] + f * mm0[1];
    float gL2 = mm1[2] + mm0[2] + 2.f * e * mm0[3] + e * e * mm0[4];
    float gLP = mm1[3] + f * (mm0[3] + e * mm0[4]);
    float gP2 = mm1[4] + f * f * mm0[4];
#pragma unroll
    for (int off = 32; off > 0; off >>= 1) {
        gA  += __shfl_down(gA,  off);
        gP  += __shfl_down(gP,  off);
        gL2 += __shfl_down(gL2, off);
        gLP += __shfl_down(gLP, off);
        gP2 += __shfl_down(gP2, off);
    }
    if (lane == 0) {
        desc[ch] = make_float2(T0D + T0C * T1D, T0C * T1C);
        mom4[ch] = make_float4(gA, gP, gL2, gLP);
        mom1[ch] = gP2;
        unsigned long long* mp = dmask + (size_t)ch * 16;
#pragma unroll
        for (int i = 0; i < 8; ++i) { mp[i] = m0[i]; mp[8 + i] = m1[i]; }
    }
}

// Pass 2: scan 16384 chunk descs -> carries; combine moments -> mean, 1/(std+eps).
// Shuffle-based, 2 barriers total. (R9-proven.)
__global__ __launch_bounds__(K2T) void k_scan(const float2* __restrict__ desc,
                                              const float4* __restrict__ mom4,
                                              const float* __restrict__ mom1,
                                              float* __restrict__ carry,
                                              float2* __restrict__ meanstd,
                                              int nchunk, long long T) {
    const int t = threadIdx.x, lane = t & 63, wv = t >> 6;   // 16 waves
    const int per = nchunk / K2T;   // 16
    const int s = t * per;
    float D = 0.f, C = 1.f;
    for (int i = per - 1; i >= 0; --i) { float2 a = desc[s + i]; D = a.x + a.y * D; C *= a.y; }
    float sD = D, sC = C;
#pragma unroll
    for (int off = 1; off < 64; off <<= 1) {
        float tD = __shfl_down(sD, off), tC = __shfl_down(sC, off);
        if (lane + off < 64) { sD = sD + sC * tD; sC = sC * tC; }
    }
    __shared__ float2 waff[16];
    if (lane == 0) waff[wv] = make_float2(sD, sC);
    __syncthreads();
    float xw = 0.f;                              // value entering this wave from the right
    for (int w = 15; w > wv; --w) xw = waff[w].x + waff[w].y * xw;
    float S1D = __shfl_down(sD, 1), S1C = __shfl_down(sC, 1);
    if (lane == 63) { S1D = 0.f; S1C = 1.f; }
    float x = S1D + S1C * xw;                    // value entering this thread's range
    double gS = 0.0, gQ = 0.0;
    for (int i = per - 1; i >= 0; --i) {
        const int cix = s + i;
        carry[cix] = x;
        float4 m = mom4[cix];
        float p2 = mom1[cix];
        gS += (double)(m.x + x * m.y);
        gQ += (double)(m.z + 2.f * x * m.w + x * x * p2);
        float2 a = desc[cix];
        x = a.x + a.y * x;
    }
#pragma unroll
    for (int off = 32; off > 0; off >>= 1) {
        gS += __shfl_down(gS, off);
        gQ += __shfl_down(gQ, off);
    }
    __shared__ double Sa[16], Sb[16];
    if (lane == 0) { Sa[wv] = gS; Sb[wv] = gQ; }
    __syncthreads();
    if (t == 0) {
        double S = 0.0, Q = 0.0;
        for (int w = 0; w < 16; ++w) { S += Sa[w]; Q += Sb[w]; }
        double mean = S / (double)T;
        double var = Q / (double)T - mean * mean;
        double sd = sqrt(var > 0.0 ? var : 0.0);
        meanstd[0] = make_float2((float)mean, (float)(1.0 / (sd + (double)EPS_F)));
    }
}

// Pass 3: recompute from (L3-hot) r,v + mask, apply carry, normalize, nt-store out. (R5-proven.)
__global__ __launch_bounds__(NT) void k_apply(const float* __restrict__ r,
                                              const float* __restrict__ v,
                                              const unsigned long long* __restrict__ dmask,
                                              const float* __restrict__ carry,
                                              const float2* __restrict__ meanstd,
                                              float* __restrict__ out) {
    const int tid = threadIdx.x, lane = tid & 63, wv = tid >> 6;
    const int ch = blockIdx.x * 4 + wv;
    const int base = ch * CHUNK;
    const int o0 = base + lane * PL, o1 = base + TILE + lane * PL;

    float4 r00 = *(const float4*)(r + o0), r01 = *(const float4*)(r + o0 + 4);
    float4 v00 = *(const float4*)(v + o0), v01 = *(const float4*)(v + o0 + 4);
    float4 r10 = *(const float4*)(r + o1), r11 = *(const float4*)(r + o1 + 4);
    float4 v10 = *(const float4*)(v + o1), v11 = *(const float4*)(v + o1 + 4);
    const unsigned long long* mp = dmask + (size_t)ch * 16;

    float vn63_t1 = (lane == 63) ? v[base + CHUNK] : 0.f;
    float vn63_t0 = __shfl(v10.x, 0);
    const float2 ms = meanstd[0];
    const float cy = carry[ch];

    float nd0[8], nd1[8];
#pragma unroll
    for (int i = 0; i < 8; ++i) {
        nd0[i] = 1.f - (float)((mp[i] >> lane) & 1ull);
        nd1[i] = 1.f - (float)((mp[8 + i] >> lane) & 1ull);
    }

    float d1[8], c1[8], sD1, sC1, S1D1, S1C1;
    tile_scan(r10, r11, v10, v11, nd1, vn63_t1, lane, d1, c1, sD1, sC1, S1D1, S1C1);
    const float T1D = __shfl(sD1, 0), T1C = __shfl(sC1, 0);
    float d0[8], c0[8], sD0, sC0, S1D0, S1C0;
    tile_scan(r00, r01, v00, v01, nd0, vn63_t0, lane, d0, c0, sD0, sC0, S1D0, S1C0);

    float o[8];
    // tile1: entry value = cy at chunk right edge
    float x = S1D1 + S1C1 * cy;
#pragma unroll
    for (int i = 7; i >= 0; --i) { x = d1[i] + c1[i] * x; o[i] = (x - ms.x) * ms.y; }
    nt_store4(out + o1,     o[0], o[1], o[2], o[3]);
    nt_store4(out + o1 + 4, o[4], o[5], o[6], o[7]);
    // tile0: entry value = A_tile1(cy)
    const float x0e = T1D + T1C * cy;
    x = S1D0 + S1C0 * x0e;
#pragma unroll
    for (int i = 7; i >= 0; --i) { x = d0[i] + c0[i] * x; o[i] = (x - ms.x) * ms.y; }
    nt_store4(out + o0,     o[0], o[1], o[2], o[3]);
    nt_store4(out + o0 + 4, o[4], o[5], o[6], o[7]);
}

extern "C" void kernel_launch(void* const* d_in, const int* in_sizes, int n_in,
                              void* d_out, int out_size, void* d_ws, size_t ws_size,
                              hipStream_t stream) {
    const float* rewards = (const float*)d_in[0];
    const float* v_pred  = (const float*)d_in[1];
    const int*   dones   = (const int*)d_in[2];
    float* out = (float*)d_out;
    const long long T = in_sizes[0];          // 16777216
    const int nchunk = (int)(T / CHUNK);      // 16384

    // workspace layout (all 16B-aligned; total ~2.5 MB of cache pollution)
    char* ws = (char*)d_ws;
    float4* mom4 = (float4*)ws;                                       // 256 KB
    float2* desc = (float2*)(ws + (size_t)nchunk * 16);               // 128 KB
    float*  mom1 = (float*)(ws + (size_t)nchunk * 24);                // 64 KB
    float*  carry = (float*)(ws + (size_t)nchunk * 28);               // 64 KB
    float2* meanstd = (float2*)(ws + (size_t)nchunk * 32);            // 16 B
    unsigned long long* dmask =
        (unsigned long long*)(ws + (size_t)nchunk * 32 + 16);         // 2 MB

    hipLaunchKernelGGL(k_desc, dim3(nchunk / 4), dim3(NT), 0, stream,
                       rewards, v_pred, dones, desc, mom4, mom1, dmask);
    hipLaunchKernelGGL(k_scan, dim3(1), dim3(K2T), 0, stream,
                       desc, mom4, mom1, carry, meanstd, nchunk, T);
    hipLaunchKernelGGL(k_apply, dim3(nchunk / 4), dim3(NT), 0, stream,
                       rewards, v_pred, dmask, carry, meanstd, out);
}